// Round 8
// baseline (1982.389 us; speedup 1.0000x reference)
//
#include <hip/hip_runtime.h>
#include <hip/hip_fp16.h>
#include <stdint.h>

// ---------- types ----------
typedef _Float16 half8 __attribute__((ext_vector_type(8)));
typedef _Float16 h2v __attribute__((ext_vector_type(2)));
typedef float f32x4 __attribute__((ext_vector_type(4)));
typedef unsigned int u32x2 __attribute__((ext_vector_type(2)));

#define GLD_LDS16(gp, lp)                                                     \
  __builtin_amdgcn_global_load_lds(                                           \
      (const __attribute__((address_space(1))) void*)(gp),                    \
      (__attribute__((address_space(3))) void*)(lp), 16, 0, 0)
#define GLD_LDS4(gp, lp)                                                      \
  __builtin_amdgcn_global_load_lds(                                           \
      (const __attribute__((address_space(1))) void*)(gp),                    \
      (__attribute__((address_space(3))) void*)(lp), 4, 0, 0)

// ---------- x convert: fp32 (harness upcast) -> fp16 ----------
__global__ void xcvt_kernel(const float* __restrict__ in, __half* __restrict__ out) {
  const size_t i = ((size_t)blockIdx.x * 256 + threadIdx.x) * 4;
  float4 v = *(const float4*)(in + i);
  __half2* o = (__half2*)(out + i);
  o[0] = __floats2half2_rn(v.x, v.y);
  o[1] = __floats2half2_rn(v.z, v.w);
}

// ---------- repack: qweight [K][N/8] -> pair-dword layout ----------
// Output dword index: ((t*N + col)*8 + p'*2 + d), where the stored dword is
// the 8 k-nibbles of qrow q = t*8 + p + 4d for column col, with bank-swizzle
// p' = p ^ ((col>>2)&3).  Nibble placement within the dword: nibble of
// k=8q+tt at bits 4*(tt>>1) + 16*(tt&1)  (so (p>>4j)&0x000F000F = k-pair 2j).
// One b64 LDS read then yields both kk dwords (d=0,1) for a column.
__global__ void repack_kernel(const int* __restrict__ qw, uint32_t* __restrict__ rp, int P) {
  const int N = P * 8;
  const int t = blockIdx.y;                       // K-step (64 k)
  const int col = blockIdx.x * 32 + (threadIdx.x >> 3);
  const int pp = (threadIdx.x >> 1) & 3;          // stored slot p'
  const int d = threadIdx.x & 1;
  const int p = pp ^ ((col >> 2) & 3);
  const int q = t * 8 + p + 4 * d;                // global qrow
  const int j8 = col >> 3;
  const int sh = (col & 7) * 4;
  const int* src = qw + (size_t)(q * 8) * P + j8;
  uint32_t r = 0;
  #pragma unroll
  for (int tt = 0; tt < 8; ++tt) {
    uint32_t w = ((uint32_t)src[tt * P] >> sh) & 15u;
    r |= w << (4 * (tt >> 1) + 16 * (tt & 1));
  }
  rp[((size_t)t * N + col) * 8 + pp * 2 + d] = r;  // fully coalesced per wave
}

// ---------- smz: per (group, col) pack (s_bits, (1024+z)_bits) ----------
__global__ void smz_kernel(const float* __restrict__ sc, const int* __restrict__ qz,
                           uint32_t* __restrict__ smz, int P) {
  const int N = P * 8;
  const int n = blockIdx.x * 256 + threadIdx.x;
  const int g = blockIdx.y;
  uint32_t sbits = __half_as_ushort(__float2half(sc[(size_t)g * N + n]));  // exact
  uint32_t z = ((uint32_t)qz[(size_t)g * P + (n >> 3)] >> ((n & 7) * 4)) & 15u;
  uint32_t hz = 0x6400u | z;  // fp16(1024+z), exact
  smz[(size_t)g * N + n] = sbits | (hz << 16);
}

// ---------- dequant 8 nibbles -> half8 (native pk-f16 ops) ----------
union U32H2 { uint32_t u; h2v h; };
__device__ inline h2v bith2(uint32_t u) { U32H2 t; t.u = u; return t.h; }
__device__ inline half8 dequant8(uint32_t p, h2v s, h2v z) {
  U32H2 t0, t1, t2, t3;
  t0.u = (p & 0x000F000Fu) | 0x64006400u;
  t1.u = ((p >> 4) & 0x000F000Fu) | 0x64006400u;
  t2.u = ((p >> 8) & 0x000F000Fu) | 0x64006400u;
  t3.u = ((p >> 12) & 0x000F000Fu) | 0x64006400u;
  h2v v0 = (t0.h - z) * s;   // v_pk_sub_f16 (exact) + v_pk_mul_f16 (1 rounding)
  h2v v1 = (t1.h - z) * s;
  h2v v2 = (t2.h - z) * s;
  h2v v3 = (t3.h - z) * s;
  half8 r = {v0.x, v0.y, v1.x, v1.y, v2.x, v2.y, v3.x, v3.y};
  return r;
}

// ---------- fused AWQ GEMM ----------
// Block: 128 rows x 2 tiles of 128 cols (tile tl at n0 + tl*T1OFF).
// Waves 2x2: wave (h=wv>>1, q=wv&1) owns rows h*64..+63, cols q*64..+63 of
// BOTH tiles (64 x 128 output) -> block A-LDS-read traffic halved vs 1x4.
// A staged in LDS (XOR-swizzled source, proven layout); B staged in the
// pair-dword layout (linear staging) and read via conflict-free ds_read_b64
// (one read = both kk dwords of a column). SMZ staged via LDS double buffer.
// Triple-buffered A/B staging, ONE s_barrier per K-step preceded by a COUNTED
// s_waitcnt vmcnt(6/7) so two 6/7-op staging batches stay in flight (T3/T4).
template <int KDIM, int NW, int T1OFF, int OW, bool SILU, int BXS>
__global__ __launch_bounds__(256, 2) void awq_gemm(const __half* __restrict__ A,
                                                   const uint32_t* __restrict__ RP,
                                                   const uint32_t* __restrict__ SMZ,
                                                   void* __restrict__ OUT) {
  constexpr int ABUF = 128 * 64 * 2;          // 16384 B per A buffer
  constexpr int BBUF = 2 * 1024 * 4;          // 8192 B per B buffer (2 tiles x 1024 dw)
  constexpr int BOFF = 3 * ABUF;              // 49152
  constexpr int ZOFF = BOFF + 3 * BBUF;       // 73728; smz double buffer 2x1024
  __shared__ __align__(16) unsigned char smem[ZOFF + 2048];

  const int tid = threadIdx.x;
  const int l = tid & 63;
  const int wv = tid >> 6;
  const int h = wv >> 1;        // row half
  const int q = wv & 1;         // col half
  const int l15 = l & 15;
  const int l4 = l >> 4;

  const int row0 = blockIdx.y * 128;
  const int n0 = blockIdx.x * BXS;

  // A staging sources (swizzled: LDS chunk slot c at row m holds k-chunk c^(m&7))
  const __half* asrc[4];
  #pragma unroll
  for (int it = 0; it < 4; ++it) {
    int m = it * 32 + (tid >> 3);
    int cs = tid & 7;
    int kc = cs ^ (m & 7);
    asrc[it] = A + (size_t)(row0 + m) * KDIM + kc * 8;
  }

  // B staging sources: step-t slice of tile tl is 4KB contiguous (linear stage)
  const uint32_t* bsrc[2];
  #pragma unroll
  for (int tl = 0; tl < 2; ++tl)
    bsrc[tl] = RP + ((size_t)(n0 + tl * T1OFF)) * 8 + tid * 4;

  // SMZ staging source: thread covers (tile = tid>>7, col offset tid&127)
  const uint32_t* zsrc = SMZ + n0 + (size_t)(tid >> 7) * T1OFF + (tid & 127);

  f32x4 acc[2][4][4];  // [tile][fi][mf]
  const f32x4 zero4 = {0.f, 0.f, 0.f, 0.f};
  #pragma unroll
  for (int tl = 0; tl < 2; ++tl)
    #pragma unroll
    for (int fi = 0; fi < 4; ++fi)
      #pragma unroll
      for (int mf = 0; mf < 4; ++mf) acc[tl][fi][mf] = zero4;

  uint32_t s2[2][4], z2[2][4];
  constexpr int NSTEP = KDIM / 64;

  // lane-constant LDS offsets
  const int aoff0 = (h * 64 + l15) * 128 + ((0 * 4 + l4) ^ (l15 & 7)) * 16;  // kk=0
  const int aoff1 = (h * 64 + l15) * 128 + ((1 * 4 + l4) ^ (l15 & 7)) * 16;  // kk=1
  const int boff = (q * 64 + l15) * 32 + (l4 ^ ((l15 >> 2) & 3)) * 8;
  const int zidx = q * 64 + l15;  // + tl*128 + fi*16

  // ---- prologue: batch(0) [A,B,smz g0] then batch(1) [A,B] ----
  #pragma unroll
  for (int it = 0; it < 4; ++it)
    GLD_LDS16(asrc[it], &smem[it * 4096 + tid * 16]);
  #pragma unroll
  for (int tl = 0; tl < 2; ++tl)
    GLD_LDS16(bsrc[tl], &smem[BOFF + tl * 4096 + tid * 16]);
  GLD_LDS4(zsrc, &smem[ZOFF + tid * 4]);
  #pragma unroll
  for (int it = 0; it < 4; ++it)
    GLD_LDS16(asrc[it] + 64, &smem[ABUF + it * 4096 + tid * 16]);
  #pragma unroll
  for (int tl = 0; tl < 2; ++tl)
    GLD_LDS16(bsrc[tl] + (size_t)NW * 8, &smem[BOFF + BBUF + tl * 4096 + tid * 16]);

  int cur = 0, stg = 2;  // buf(t%3), buf((t+2)%3)
  for (int t = 0; t < NSTEP; ++t) {
    // counted wait: drain batch(t); batch(t+1) = 6 (+1 if t+1 even) in flight
    if (t == NSTEP - 1)      asm volatile("s_waitcnt vmcnt(0)" ::: "memory");
    else if (t & 1)          asm volatile("s_waitcnt vmcnt(7)" ::: "memory");
    else                     asm volatile("s_waitcnt vmcnt(6)" ::: "memory");
    __builtin_amdgcn_s_barrier();

    // issue batch(t+2) into buf stg
    if (t + 2 < NSTEP) {
      #pragma unroll
      for (int it = 0; it < 4; ++it)
        GLD_LDS16(asrc[it] + (size_t)(t + 2) * 64, &smem[stg * ABUF + it * 4096 + tid * 16]);
      #pragma unroll
      for (int tl = 0; tl < 2; ++tl)
        GLD_LDS16(bsrc[tl] + (size_t)(t + 2) * NW * 8,
                  &smem[BOFF + stg * BBUF + tl * 4096 + tid * 16]);
      if (((t + 2) & 1) == 0) {  // smz for group (t+2)/2 into buf ((t+2)/2)&1
        const int g = (t + 2) >> 1;
        GLD_LDS4(zsrc + (size_t)g * NW, &smem[ZOFF + (g & 1) * 1024 + tid * 4]);
      }
    }

    if ((t & 1) == 0) {  // group boundary: unpack s/z from smz LDS buffer
      const uint32_t* zl = (const uint32_t*)&smem[ZOFF + ((t >> 1) & 1) * 1024];
      #pragma unroll
      for (int tl = 0; tl < 2; ++tl)
        #pragma unroll
        for (int fi = 0; fi < 4; ++fi) {
          uint32_t u = zl[tl * 128 + fi * 16 + zidx];
          uint32_t lo = u & 0xFFFFu;
          s2[tl][fi] = lo | (lo << 16);
          z2[tl][fi] = (u & 0xFFFF0000u) | (u >> 16);
        }
    }

    // B pair-dwords: one conflict-free b64 per (tile, col-frag) = both kk
    u32x2 bq[2][4];
    const unsigned char* bbase = &smem[BOFF + cur * BBUF];
    #pragma unroll
    for (int tl = 0; tl < 2; ++tl)
      #pragma unroll
      for (int fi = 0; fi < 4; ++fi)
        bq[tl][fi] = *(const u32x2*)&bbase[boff + tl * 4096 + fi * 512];

    const unsigned char* abase = &smem[cur * ABUF];
    #pragma unroll
    for (int kk = 0; kk < 2; ++kk) {
      half8 a[4];
      const int ao = kk ? aoff1 : aoff0;
      #pragma unroll
      for (int mf = 0; mf < 4; ++mf)
        a[mf] = *(const half8*)(abase + ao + mf * 2048);
      #pragma unroll
      for (int tl = 0; tl < 2; ++tl)
        #pragma unroll
        for (int fi = 0; fi < 4; ++fi) {
          half8 b = dequant8(kk ? bq[tl][fi].y : bq[tl][fi].x,
                             bith2(s2[tl][fi]), bith2(z2[tl][fi]));
          #pragma unroll
          for (int mf = 0; mf < 4; ++mf)
            acc[tl][fi][mf] =
                __builtin_amdgcn_mfma_f32_16x16x32_f16(a[mf], b, acc[tl][fi][mf], 0, 0, 0);
        }
    }

    cur = (cur == 2) ? 0 : cur + 1;
    stg = (stg == 2) ? 0 : stg + 1;
  }

  // epilogue
  if (SILU) {
    __half* O = (__half*)OUT;
    #pragma unroll
    for (int fi = 0; fi < 4; ++fi)
      #pragma unroll
      for (int mf = 0; mf < 4; ++mf)
        #pragma unroll
        for (int r = 0; r < 4; ++r) {
          int row = row0 + h * 64 + mf * 16 + l4 * 4 + r;
          int col = n0 + q * 64 + fi * 16 + l15;
          float gf = __half2float(__float2half(acc[0][fi][mf][r]));  // gate fp16 cast
          float uf = __half2float(__float2half(acc[1][fi][mf][r]));  // up fp16 cast
          float sig = 1.f / (1.f + __expf(-gf));
          float sil = __half2float(__float2half(gf * sig));          // silu fp16 cast
          O[(size_t)row * OW + col] = __float2half(sil * uf);        // intermediate fp16
        }
  } else {
    float* O = (float*)OUT;
    #pragma unroll
    for (int tl = 0; tl < 2; ++tl)
      #pragma unroll
      for (int fi = 0; fi < 4; ++fi)
        #pragma unroll
        for (int mf = 0; mf < 4; ++mf)
          #pragma unroll
          for (int r = 0; r < 4; ++r) {
            int row = row0 + h * 64 + mf * 16 + l4 * 4 + r;
            int col = n0 + tl * T1OFF + q * 64 + fi * 16 + l15;
            O[(size_t)row * OW + col] = __half2float(__float2half(acc[tl][fi][mf][r]));
          }
  }
}

// ---------- launch ----------
// Workspace phase-aliasing (stay under round-1-proven-safe 263,397,376 B):
//   phase 1 (through GEMM1): interm | rp_gu | smz_gu | xh   = 256,688,128 B
//   phase 2 (after GEMM1):   interm | rp_dn | smz_dn        = 191,258,624 B
extern "C" void kernel_launch(void* const* d_in, const int* in_sizes, int n_in,
                              void* d_out, int out_size, void* d_ws, size_t ws_size,
                              hipStream_t stream) {
  const float* x_f32 = (const float*)d_in[0];          // harness upcasts fp16 -> fp32
  const int* qw_gu = (const int*)d_in[1];
  const int* qz_gu = (const int*)d_in[2];
  const float* sc_gu = (const float*)d_in[3];          // fp32 (upcast)
  const int* qw_dn = (const int*)d_in[4];
  const int* qz_dn = (const int*)d_in[5];
  const float* sc_dn = (const float*)d_in[6];          // fp32 (upcast)

  char* ws = (char*)d_ws;
  __half* interm   = (__half*)ws;                      // 155,189,248
  uint32_t* rp_gu  = (uint32_t*)(ws + 155189248ull);   // 67,895,296
  uint32_t* smz_gu = (uint32_t*)(ws + 223084544ull);   // 4,243,456
  __half* xh       = (__half*)(ws + 227328000ull);     // 29,360,128
  uint32_t* rp_dn  = (uint32_t*)(ws + 155189248ull);   // aliases rp_gu
  uint32_t* smz_dn = (uint32_t*)(ws + 189136896ull);

  // ---- phase 1: prep + GEMM1 ----
  xcvt_kernel<<<14336, 256, 0, stream>>>(x_f32, xh);
  repack_kernel<<<dim3(1184, 56), 256, 0, stream>>>(qw_gu, rp_gu, 4736);   // 37888 cols, 56 steps
  smz_kernel<<<dim3(148, 28), 256, 0, stream>>>(sc_gu, qz_gu, smz_gu, 4736);

  // GEMM1: blocks stride 128 gate cols (paired up cols at +18944)
  awq_gemm<3584, 37888, 18944, 18944, true, 128>
      <<<dim3(148, 32), 256, 0, stream>>>(xh, rp_gu, smz_gu, (void*)interm);

  // ---- phase 2: prep + GEMM2 (aliased scratch) ----
  repack_kernel<<<dim3(112, 296), 256, 0, stream>>>(qw_dn, rp_dn, 448);    // 3584 cols, 296 steps
  smz_kernel<<<dim3(14, 148), 256, 0, stream>>>(sc_dn, qz_dn, smz_dn, 448);

  // GEMM2: blocks stride 256 cols (two adjacent 128-col tiles)
  awq_gemm<18944, 3584, 128, 3584, false, 256>
      <<<dim3(14, 32), 256, 0, stream>>>(interm, rp_dn, smz_dn, d_out);
}

// Round 9
// 1608.690 us; speedup vs baseline: 1.2323x; 1.2323x over previous
//
#include <hip/hip_runtime.h>
#include <hip/hip_fp16.h>
#include <stdint.h>

// ---------- types ----------
typedef _Float16 half8 __attribute__((ext_vector_type(8)));
typedef _Float16 h2v __attribute__((ext_vector_type(2)));
typedef float f32x4 __attribute__((ext_vector_type(4)));

#define GLD_LDS16(gp, lp)                                                     \
  __builtin_amdgcn_global_load_lds(                                           \
      (const __attribute__((address_space(1))) void*)(gp),                    \
      (__attribute__((address_space(3))) void*)(lp), 16, 0, 0)
#define GLD_LDS4(gp, lp)                                                      \
  __builtin_amdgcn_global_load_lds(                                           \
      (const __attribute__((address_space(1))) void*)(gp),                    \
      (__attribute__((address_space(3))) void*)(lp), 4, 0, 0)

// ---------- x convert: fp32 (harness upcast) -> fp16 ----------
__global__ void xcvt_kernel(const float* __restrict__ in, __half* __restrict__ out) {
  const size_t i = ((size_t)blockIdx.x * 256 + threadIdx.x) * 4;
  float4 v = *(const float4*)(in + i);
  __half2* o = (__half2*)(out + i);
  o[0] = __floats2half2_rn(v.x, v.y);
  o[1] = __floats2half2_rn(v.z, v.w);
}

// ---------- repack: qweight [K][N/8] col-packed -> [K/8][N] k-packed ----------
// Output dword for (q, n): nibble of k=8q+t placed at bits 4*(t>>1) + 16*(t&1),
// so that (p >> 4j) & 0x000F000F gives halves (k=2j, k=2j+1).
__global__ void repack_kernel(const int* __restrict__ qw, uint32_t* __restrict__ rp, int P) {
  const int N = P * 8;
  const int n = blockIdx.x * 256 + threadIdx.x;
  const int j8 = n >> 3;
  const int sh = (n & 7) * 4;
  #pragma unroll
  for (int qi = 0; qi < 4; ++qi) {
    const int q = blockIdx.y * 4 + qi;
    const int* src = qw + (size_t)(q * 8) * P + j8;
    uint32_t r = 0;
    #pragma unroll
    for (int t = 0; t < 8; ++t) {
      uint32_t w = ((uint32_t)src[t * P] >> sh) & 15u;
      r |= w << (4 * (t >> 1) + 16 * (t & 1));
    }
    rp[(size_t)q * N + n] = r;
  }
}

// ---------- smz: per (group, col) pack (s_bits, (1024+z)_bits) ----------
__global__ void smz_kernel(const float* __restrict__ sc, const int* __restrict__ qz,
                           uint32_t* __restrict__ smz, int P) {
  const int N = P * 8;
  const int n = blockIdx.x * 256 + threadIdx.x;
  const int g = blockIdx.y;
  uint32_t sbits = __half_as_ushort(__float2half(sc[(size_t)g * N + n]));  // exact
  uint32_t z = ((uint32_t)qz[(size_t)g * P + (n >> 3)] >> ((n & 7) * 4)) & 15u;
  uint32_t hz = 0x6400u | z;  // fp16(1024+z), exact
  smz[(size_t)g * N + n] = sbits | (hz << 16);
}

// ---------- dequant 8 nibbles -> half8 (pk-f16 ops, dword-wise construction) ----------
union U32H2 { uint32_t u; h2v h; };
__device__ inline h2v bith2(uint32_t u) { U32H2 t; t.u = u; return t.h; }
__device__ inline uint32_t h2bit(h2v h) { U32H2 t; t.h = h; return t.u; }
__device__ inline half8 dequant8(uint32_t p, h2v s, h2v z) {
  union { uint32_t u[4]; half8 v; } r;
  r.u[0] = h2bit((bith2((p & 0x000F000Fu) | 0x64006400u) - z) * s);
  r.u[1] = h2bit((bith2(((p >> 4) & 0x000F000Fu) | 0x64006400u) - z) * s);
  r.u[2] = h2bit((bith2(((p >> 8) & 0x000F000Fu) | 0x64006400u) - z) * s);
  r.u[3] = h2bit((bith2(((p >> 12) & 0x000F000Fu) | 0x64006400u) - z) * s);
  return r.v;  // v_pk_sub_f16 (exact) + v_pk_mul_f16 (1 rounding) per dword
}

// ---------- fused AWQ GEMM ----------
// R7-proven structure: 128 rows x NT tiles of 128 cols per block
// (tile tl at n0 + tl*T1OFF, n0 = blockIdx.x * BXS). 4 waves, 1x4 split:
// each wave owns 128 rows x 32 cols of BOTH tiles (B dequant amortized
// over 8 row-fragments -- R8 showed halving this amortization regresses).
// Triple-buffered staging (A, B packed dwords, SMZ) via global_load_lds;
// ONE s_barrier per K-step preceded by COUNTED s_waitcnt vmcnt(6/7) (T3/T4).
// NEW (R9): s_setprio(1) around the dequant+MFMA cluster (T5) -- 2 blocks/CU
// give block-level phase diversity for the CU scheduler to exploit.
template <int KDIM, int NW, int T1OFF, int OW, bool SILU, int NT, int BXS>
__global__ __launch_bounds__(256, 2) void awq_gemm(const __half* __restrict__ A,
                                                   const uint32_t* __restrict__ RP,
                                                   const uint32_t* __restrict__ SMZ,
                                                   void* __restrict__ OUT) {
  constexpr int ABUF = 128 * 64 * 2;          // 16384 B per A buffer
  constexpr int BBUF = NT * 8 * 128 * 4;      // 4096*NT per B buffer
  constexpr int BOFF = 3 * ABUF;              // 49152
  constexpr int ZOFF = BOFF + 3 * BBUF;       // smz double buffer (2 x 1024 B)
  __shared__ __align__(16) unsigned char smem[ZOFF + 2048];

  const int tid = threadIdx.x;
  const int l = tid & 63;
  const int wv = tid >> 6;
  const int l15 = l & 15;
  const int l4 = l >> 4;

  const int row0 = blockIdx.y * 128;
  const int n0 = blockIdx.x * BXS;

  // A staging sources (swizzled: LDS chunk slot c at row m holds k-chunk c^(m&7))
  const __half* asrc[4];
  #pragma unroll
  for (int it = 0; it < 4; ++it) {
    int m = it * 32 + (tid >> 3);
    int cs = tid & 7;
    int kc = cs ^ (m & 7);
    asrc[it] = A + (size_t)(row0 + m) * KDIM + kc * 8;
  }

  // B staging sources: LDS dword d of qrow qr holds RP col (d ^ S(qr))
  const uint32_t* bsrc[NT];
  #pragma unroll
  for (int it = 0; it < NT; ++it) {
    int idx = it * 256 + tid;
    int tile = idx >> 8;
    int qr = (idx >> 5) & 7;
    int l32 = idx & 31;
    int S = ((qr & 1) << 4) | ((qr >> 1) << 2);
    bsrc[it] = RP + (size_t)qr * NW + n0 + tile * T1OFF + ((l32 * 4) ^ S);
  }

  // SMZ staging source: thread covers (tile = tid>>7, col offset tid&127)
  const uint32_t* zsrc = SMZ + n0 + (size_t)(tid >> 7) * T1OFF + (tid & 127);

  f32x4 acc[NT][2][8];
  const f32x4 zero4 = {0.f, 0.f, 0.f, 0.f};
  #pragma unroll
  for (int t = 0; t < NT; ++t)
    #pragma unroll
    for (int nf = 0; nf < 2; ++nf)
      #pragma unroll
      for (int mf = 0; mf < 8; ++mf) acc[t][nf][mf] = zero4;

  uint32_t s2[NT][2], z2[NT][2];
  constexpr int NSTEP = KDIM / 64;

  // ---- prologue: batch(0) [A,B,smz g0] then batch(1) [A,B] ----
  #pragma unroll
  for (int it = 0; it < 4; ++it)
    GLD_LDS16(asrc[it], &smem[it * 4096 + tid * 16]);
  #pragma unroll
  for (int it = 0; it < NT; ++it)
    GLD_LDS16(bsrc[it], &smem[BOFF + (it * 256 + tid) * 16]);
  GLD_LDS4(zsrc, &smem[ZOFF + tid * 4]);
  #pragma unroll
  for (int it = 0; it < 4; ++it)
    GLD_LDS16(asrc[it] + 64, &smem[ABUF + it * 4096 + tid * 16]);
  #pragma unroll
  for (int it = 0; it < NT; ++it)
    GLD_LDS16(bsrc[it] + (size_t)8 * NW, &smem[BOFF + BBUF + (it * 256 + tid) * 16]);

  int cur = 0, stg = 2;  // buf(t%3), buf((t+2)%3)
  for (int t = 0; t < NSTEP; ++t) {
    // counted wait: drain batch(t); batch(t+1) = 6 (+1 if t+1 even) in flight
    if (t == NSTEP - 1)      asm volatile("s_waitcnt vmcnt(0)" ::: "memory");
    else if (t & 1)          asm volatile("s_waitcnt vmcnt(7)" ::: "memory");
    else                     asm volatile("s_waitcnt vmcnt(6)" ::: "memory");
    __builtin_amdgcn_s_barrier();

    // issue batch(t+2) into buf stg
    if (t + 2 < NSTEP) {
      #pragma unroll
      for (int it = 0; it < 4; ++it)
        GLD_LDS16(asrc[it] + (size_t)(t + 2) * 64, &smem[stg * ABUF + it * 4096 + tid * 16]);
      #pragma unroll
      for (int it = 0; it < NT; ++it)
        GLD_LDS16(bsrc[it] + (size_t)(t + 2) * 8 * NW,
                  &smem[BOFF + stg * BBUF + (it * 256 + tid) * 16]);
      if (((t + 2) & 1) == 0) {  // smz for group (t+2)/2 into buf ((t+2)/2)&1
        const int g = (t + 2) >> 1;
        GLD_LDS4(zsrc + (size_t)g * NW, &smem[ZOFF + (g & 1) * 1024 + tid * 4]);
      }
    }

    if ((t & 1) == 0) {  // group boundary: unpack s/z from smz LDS buffer
      const uint32_t* zl = (const uint32_t*)&smem[ZOFF + ((t >> 1) & 1) * 1024];
      #pragma unroll
      for (int tile = 0; tile < NT; ++tile)
        #pragma unroll
        for (int nf = 0; nf < 2; ++nf) {
          uint32_t u = zl[tile * 128 + wv * 32 + nf * 16 + l15];
          uint32_t lo = u & 0xFFFFu;
          s2[tile][nf] = lo | (lo << 16);
          z2[tile][nf] = (u & 0xFFFF0000u) | (u >> 16);
        }
    }

    // B dwords from LDS (read swizzle matches staged source swizzle)
    uint32_t bq[2][NT][2];
    const int bro = wv * 32 + l15;
    const unsigned char* bbase = &smem[BOFF + cur * BBUF];
    #pragma unroll
    for (int kk = 0; kk < 2; ++kk) {
      const int Sl = ((l4 & 1) << 4) | (kk << 3) | ((l4 >> 1) << 2);
      #pragma unroll
      for (int tile = 0; tile < NT; ++tile)
        #pragma unroll
        for (int nf = 0; nf < 2; ++nf)
          bq[kk][tile][nf] = *(const uint32_t*)&bbase[
              (((tile * 8 + kk * 4 + l4) * 128) + ((bro + nf * 16) ^ Sl)) * 4];
    }

    const unsigned char* abase = &smem[cur * ABUF];
    __builtin_amdgcn_s_setprio(1);   // T5: favor this wave through the MFMA cluster
    #pragma unroll
    for (int kk = 0; kk < 2; ++kk) {
      half8 a[8];
      #pragma unroll
      for (int mf = 0; mf < 8; ++mf) {
        int m = mf * 16 + l15;
        int chunk = (kk * 4 + l4) ^ (l15 & 7);
        a[mf] = *(const half8*)(abase + m * 128 + chunk * 16);
      }
      #pragma unroll
      for (int tile = 0; tile < NT; ++tile)
        #pragma unroll
        for (int nf = 0; nf < 2; ++nf) {
          half8 b = dequant8(bq[kk][tile][nf], bith2(s2[tile][nf]), bith2(z2[tile][nf]));
          #pragma unroll
          for (int mf = 0; mf < 8; ++mf)
            acc[tile][nf][mf] =
                __builtin_amdgcn_mfma_f32_16x16x32_f16(a[mf], b, acc[tile][nf][mf], 0, 0, 0);
        }
    }
    __builtin_amdgcn_s_setprio(0);

    cur = (cur == 2) ? 0 : cur + 1;
    stg = (stg == 2) ? 0 : stg + 1;
  }

  // epilogue
  if (SILU) {
    __half* O = (__half*)OUT;
    #pragma unroll
    for (int nf = 0; nf < 2; ++nf)
      #pragma unroll
      for (int mf = 0; mf < 8; ++mf)
        #pragma unroll
        for (int r = 0; r < 4; ++r) {
          int row = row0 + mf * 16 + l4 * 4 + r;
          int col = n0 + wv * 32 + nf * 16 + l15;
          float gf = __half2float(__float2half(acc[0][nf][mf][r]));  // gate_up fp16 cast
          float uf = __half2float(__float2half(acc[1][nf][mf][r]));
          float sig = 1.f / (1.f + __expf(-gf));
          float sil = __half2float(__float2half(gf * sig));          // silu fp16 cast
          O[(size_t)row * OW + col] = __float2half(sil * uf);        // intermediate fp16
        }
  } else {
    float* O = (float*)OUT;
    #pragma unroll
    for (int tile = 0; tile < NT; ++tile)
      #pragma unroll
      for (int nf = 0; nf < 2; ++nf)
        #pragma unroll
        for (int mf = 0; mf < 8; ++mf)
          #pragma unroll
          for (int r = 0; r < 4; ++r) {
            int row = row0 + mf * 16 + l4 * 4 + r;
            int col = n0 + tile * T1OFF + wv * 32 + nf * 16 + l15;
            O[(size_t)row * OW + col] = __half2float(__float2half(acc[tile][nf][mf][r]));
          }
  }
}

// ---------- launch ----------
// Workspace phase-aliasing (stay under round-1-proven-safe 263,397,376 B):
//   phase 1 (through GEMM1): interm | rp_gu | smz_gu | xh   = 256,688,128 B
//   phase 2 (after GEMM1):   interm | rp_dn | smz_dn        = 191,258,624 B
extern "C" void kernel_launch(void* const* d_in, const int* in_sizes, int n_in,
                              void* d_out, int out_size, void* d_ws, size_t ws_size,
                              hipStream_t stream) {
  const float* x_f32 = (const float*)d_in[0];          // harness upcasts fp16 -> fp32
  const int* qw_gu = (const int*)d_in[1];
  const int* qz_gu = (const int*)d_in[2];
  const float* sc_gu = (const float*)d_in[3];          // fp32 (upcast)
  const int* qw_dn = (const int*)d_in[4];
  const int* qz_dn = (const int*)d_in[5];
  const float* sc_dn = (const float*)d_in[6];          // fp32 (upcast)

  char* ws = (char*)d_ws;
  __half* interm   = (__half*)ws;                      // 155,189,248
  uint32_t* rp_gu  = (uint32_t*)(ws + 155189248ull);   // 67,895,296
  uint32_t* smz_gu = (uint32_t*)(ws + 223084544ull);   // 4,243,456
  __half* xh       = (__half*)(ws + 227328000ull);     // 29,360,128
  uint32_t* rp_dn  = (uint32_t*)(ws + 155189248ull);   // aliases rp_gu
  uint32_t* smz_dn = (uint32_t*)(ws + 189136896ull);

  // ---- phase 1: prep + GEMM1 ----
  xcvt_kernel<<<14336, 256, 0, stream>>>(x_f32, xh);
  repack_kernel<<<dim3(148, 112), 256, 0, stream>>>(qw_gu, rp_gu, 4736);
  smz_kernel<<<dim3(148, 28), 256, 0, stream>>>(sc_gu, qz_gu, smz_gu, 4736);

  // GEMM1: blocks stride 128 gate cols (paired up cols at +18944)
  awq_gemm<3584, 37888, 18944, 18944, true, 2, 128>
      <<<dim3(148, 32), 256, 0, stream>>>(xh, rp_gu, smz_gu, (void*)interm);

  // ---- phase 2: prep + GEMM2 (aliased scratch) ----
  repack_kernel<<<dim3(14, 592), 256, 0, stream>>>(qw_dn, rp_dn, 448);
  smz_kernel<<<dim3(14, 148), 256, 0, stream>>>(sc_dn, qz_dn, smz_dn, 448);

  // GEMM2: blocks stride 256 cols (two adjacent 128-col tiles)
  awq_gemm<18944, 3584, 128, 3584, false, 2, 256>
      <<<dim3(14, 32), 256, 0, stream>>>(interm, rp_dn, smz_dn, d_out);
}